// Round 15
// baseline (378.752 us; speedup 1.0000x reference)
//
#include <hip/hip_runtime.h>
#include <math.h>

// LSTMLightweight on MI355X (R15: two independent chains per wave, MFMA).
//   x[B,T,1] -> linear_in(1->16)+ReLU -> LSTM0(16) -> LSTM1(16) -> fc(16->8)+ReLU -> fc(8->1)
// R12-R14 lesson: single-chain waves are dependency-latency-bound (1900 cyc/step,
// VALU 36%, Mfma 9.3% — 64% stall). Extra waves don't help (R13); coupled L0/L1
// interleave helps 10% (R14). R15: each wave carries TWO fully independent
// batch chains (EPB=32, grid=B/32=256). Weights/biases (MFMA A-frags, C-init)
// are SHARED across chains — a second chain costs only ~55 regs of state.
// Per iteration: 4 independent streams {L0(t+1),L1(t)}x{ch0,ch1}; all 48 MFMAs
// issue back-to-back, then 4 combines — each stream's stalls hide under the
// others' issue. Zero LDS/barriers in the loop.
// Math identical to R12/R14 (absmax 2e-3): K-permuted A so B is lane-local
// (k=8g+i -> W_ih[.][4g+i] | W_hh[.][4g+i-4]; D row=4*(lane>>4)+q, col=lane&15),
// split-bf16 3-product MFMA, bias in C-init.

#define L2E 1.4426950408889634f
#define EPB 32        // elements per wave = 2 chains x 16 (MFMA N)

typedef short bf16x8 __attribute__((ext_vector_type(8)));
typedef float f32x4  __attribute__((ext_vector_type(4)));
typedef int   i32x4  __attribute__((ext_vector_type(4)));

__device__ __forceinline__ float sigm(float v) {
    return __builtin_amdgcn_rcpf(1.0f + __builtin_amdgcn_exp2f(-L2E * v));
}
__device__ __forceinline__ float tanh_(float v) {
    // tanh(v) = 1 - 2/(exp(2v)+1); saturates correctly at +-inf
    return 1.0f - 2.0f * __builtin_amdgcn_rcpf(1.0f + __builtin_amdgcn_exp2f((2.0f * L2E) * v));
}
// bf16 split helpers (truncation split: hi = top 16 bits; lo = bf16(v - hi))
__device__ __forceinline__ float hif(float a) {
    return __uint_as_float(__float_as_uint(a) & 0xFFFF0000u);
}
__device__ __forceinline__ unsigned pk2hi(float a, float b) {
    return (__float_as_uint(a) >> 16) | (__float_as_uint(b) & 0xFFFF0000u);
}
__device__ __forceinline__ unsigned pk2lo(float a, float b) {
    const float ra = a - hif(a), rb = b - hif(b);
    return (__float_as_uint(ra) >> 16) | (__float_as_uint(rb) & 0xFFFF0000u);
}
__device__ __forceinline__ short bhi(float a) { return (short)(__float_as_uint(a) >> 16); }
__device__ __forceinline__ bf16x8 mkfrag(unsigned w0, unsigned w1, unsigned w2, unsigned w3) {
    i32x4 t = {(int)w0, (int)w1, (int)w2, (int)w3};
    return __builtin_bit_cast(bf16x8, t);
}

// one layer's gate MFMAs: acc[m] = bias[m] + split-bf16(A)·B
#define GATES(ACC, AHI, ALO, BIAS, BH, BL)                                             \
    _Pragma("unroll")                                                                  \
    for (int m = 0; m < 4; ++m) {                                                      \
        ACC[m] = BIAS[m];                                                              \
        ACC[m] = __builtin_amdgcn_mfma_f32_16x16x32_bf16(ALO[m], BH, ACC[m], 0, 0, 0); \
        ACC[m] = __builtin_amdgcn_mfma_f32_16x16x32_bf16(AHI[m], BL, ACC[m], 0, 0, 0); \
        ACC[m] = __builtin_amdgcn_mfma_f32_16x16x32_bf16(AHI[m], BH, ACC[m], 0, 0, 0); \
    }

// combine: i,f,g,o -> c,h (per q); writes HV[4] and updates CC[4]
#define COMBINE(ACC, CC, HV)                                                           \
    _Pragma("unroll")                                                                  \
    for (int q = 0; q < 4; ++q) {                                                      \
        const float ig_ = sigm(ACC[0][q]);                                             \
        const float fg_ = sigm(ACC[1][q]);                                             \
        const float gv_ = tanh_(ACC[2][q]);                                            \
        const float og_ = sigm(ACC[3][q]);                                             \
        CC[q] = fmaf(fg_, CC[q], ig_ * gv_);                                           \
        HV[q] = og_ * tanh_(CC[q]);                                                    \
    }

__global__ __launch_bounds__(64) void lstm_swp2(
    const float* __restrict__ x,
    const float* __restrict__ w_in, const float* __restrict__ b_in,
    const float* __restrict__ w_ih0, const float* __restrict__ w_hh0,
    const float* __restrict__ b_ih0, const float* __restrict__ b_hh0,
    const float* __restrict__ w_ih1, const float* __restrict__ w_hh1,
    const float* __restrict__ b_ih1, const float* __restrict__ b_hh1,
    const float* __restrict__ fc_h_w, const float* __restrict__ fc_h_b,
    const float* __restrict__ fc_o_w, const float* __restrict__ fc_o_b,
    float* __restrict__ out, int B, int T)
{
    const int lane = threadIdx.x;        // 0..63
    const int e    = lane & 15;          // element column (= A row within tile)
    const int g    = lane >> 4;          // k-group / D-row group
    const int base = blockIdx.x * EPB;

    __shared__ float htab[EPB][16];      // head exchange only

    // ---- A-fragments (shared by both chains), K-permuted, split bf16 ----
    bf16x8 a0hi[4], a0lo[4], a1hi[4], a1lo[4];
    f32x4  bias0[4], bias1[4];
    #pragma unroll
    for (int m = 0; m < 4; ++m) {
        const int r = 16 * m + e;
        #pragma unroll
        for (int i = 0; i < 8; ++i) {
            const float w0 = (i < 4) ? w_ih0[r * 16 + 4 * g + i]
                                     : w_hh0[r * 16 + 4 * g + (i - 4)];
            const float w1 = (i < 4) ? w_ih1[r * 16 + 4 * g + i]
                                     : w_hh1[r * 16 + 4 * g + (i - 4)];
            a0hi[m][i] = bhi(w0);  a0lo[m][i] = bhi(w0 - hif(w0));
            a1hi[m][i] = bhi(w1);  a1lo[m][i] = bhi(w1 - hif(w1));
        }
        const int rd = 16 * m + 4 * g;
        #pragma unroll
        for (int q = 0; q < 4; ++q) {
            bias0[m][q] = b_ih0[rd + q] + b_hh0[rd + q];
            bias1[m][q] = b_ih1[rd + q] + b_hh1[rd + q];
        }
    }
    float winq[4], binq[4];
    #pragma unroll
    for (int q = 0; q < 4; ++q) { winq[q] = w_in[4 * g + q]; binq[q] = b_in[4 * g + q]; }

    // ---- per-chain state (fully unrolled indices -> registers) ----
    float c0[2][4], c1[2][4], h1v[2][4];
    unsigned h0p[2][4];                  // h0(t) packs: hi0,hi1,lo0,lo1
    unsigned h1p[2][4];                  // h1(t-1) packs
    const float* xrow[2];
    float xv1[2];
    #pragma unroll
    for (int ch = 0; ch < 2; ++ch) {
        int r = base + 16 * ch + e; if (r >= B) r = B - 1;
        xrow[ch] = x + (size_t)r * T;
        #pragma unroll
        for (int q = 0; q < 4; ++q) {
            c0[ch][q] = 0.f; c1[ch][q] = 0.f; h1v[ch][q] = 0.f;
        }
        #pragma unroll
        for (int q = 0; q < 4; ++q) { h0p[ch][q] = 0u; h1p[ch][q] = 0u; }
    }

    // ---- prologue: L0 at t=0 for both chains (h0_{-1}=0) ----
    #pragma unroll
    for (int ch = 0; ch < 2; ++ch) {
        const float xv = xrow[ch][0];
        float xq[4];
        #pragma unroll
        for (int q = 0; q < 4; ++q) xq[q] = fmaxf(fmaf(xv, winq[q], binq[q]), 0.0f);
        const bf16x8 Bh = mkfrag(pk2hi(xq[0], xq[1]), pk2hi(xq[2], xq[3]), 0u, 0u);
        const bf16x8 Bl = mkfrag(pk2lo(xq[0], xq[1]), pk2lo(xq[2], xq[3]), 0u, 0u);
        f32x4 acc[4];
        GATES(acc, a0hi, a0lo, bias0, Bh, Bl);
        float h0v[4];
        COMBINE(acc, c0[ch], h0v);
        h0p[ch][0] = pk2hi(h0v[0], h0v[1]); h0p[ch][1] = pk2hi(h0v[2], h0v[3]);
        h0p[ch][2] = pk2lo(h0v[0], h0v[1]); h0p[ch][3] = pk2lo(h0v[2], h0v[3]);
        xv1[ch] = xrow[ch][(T > 1) ? 1 : 0];
    }

    // ---- steady state: iteration t = { L1(t) || L0(t+1) } x { ch0, ch1 } ----
    for (int t = 0; t < T - 1; ++t) {
        const int tn = (t + 2 < T) ? (t + 2) : (T - 1);
        float xn[2];
        #pragma unroll
        for (int ch = 0; ch < 2; ++ch) xn[ch] = xrow[ch][tn];   // prefetch x(t+2)

        // build all B-frags first (from pre-update packs)
        bf16x8 B0h[2], B0l[2], B1h[2], B1l[2];
        #pragma unroll
        for (int ch = 0; ch < 2; ++ch) {
            float xq[4];
            #pragma unroll
            for (int q = 0; q < 4; ++q)
                xq[q] = fmaxf(fmaf(xv1[ch], winq[q], binq[q]), 0.0f);
            B0h[ch] = mkfrag(pk2hi(xq[0], xq[1]), pk2hi(xq[2], xq[3]),
                             h0p[ch][0], h0p[ch][1]);
            B0l[ch] = mkfrag(pk2lo(xq[0], xq[1]), pk2lo(xq[2], xq[3]),
                             h0p[ch][2], h0p[ch][3]);
            B1h[ch] = mkfrag(h0p[ch][0], h0p[ch][1], h1p[ch][0], h1p[ch][1]);
            B1l[ch] = mkfrag(h0p[ch][2], h0p[ch][3], h1p[ch][2], h1p[ch][3]);
        }

        // issue all 4 independent MFMA streams back-to-back
        f32x4 acc0[2][4], acc1[2][4];
        GATES(acc0[0], a0hi, a0lo, bias0, B0h[0], B0l[0]);   // ch0 L0(t+1)
        GATES(acc1[0], a1hi, a1lo, bias1, B1h[0], B1l[0]);   // ch0 L1(t)
        GATES(acc0[1], a0hi, a0lo, bias0, B0h[1], B0l[1]);   // ch1 L0(t+1)
        GATES(acc1[1], a1hi, a1lo, bias1, B1h[1], B1l[1]);   // ch1 L1(t)

        // combines: 4 independent streams interleave on VALU/trans pipes
        float h0v[2][4];
        COMBINE(acc0[0], c0[0], h0v[0]);
        COMBINE(acc1[0], c1[0], h1v[0]);
        COMBINE(acc0[1], c0[1], h0v[1]);
        COMBINE(acc1[1], c1[1], h1v[1]);

        #pragma unroll
        for (int ch = 0; ch < 2; ++ch) {
            h0p[ch][0] = pk2hi(h0v[ch][0], h0v[ch][1]);
            h0p[ch][1] = pk2hi(h0v[ch][2], h0v[ch][3]);
            h0p[ch][2] = pk2lo(h0v[ch][0], h0v[ch][1]);
            h0p[ch][3] = pk2lo(h0v[ch][2], h0v[ch][3]);
            h1p[ch][0] = pk2hi(h1v[ch][0], h1v[ch][1]);
            h1p[ch][1] = pk2hi(h1v[ch][2], h1v[ch][3]);
            h1p[ch][2] = pk2lo(h1v[ch][0], h1v[ch][1]);
            h1p[ch][3] = pk2lo(h1v[ch][2], h1v[ch][3]);
            xv1[ch] = xn[ch];
        }
    }

    // ---- epilogue: L1(T-1) for both chains ----
    #pragma unroll
    for (int ch = 0; ch < 2; ++ch) {
        const bf16x8 Bh = mkfrag(h0p[ch][0], h0p[ch][1], h1p[ch][0], h1p[ch][1]);
        const bf16x8 Bl = mkfrag(h0p[ch][2], h0p[ch][3], h1p[ch][2], h1p[ch][3]);
        f32x4 acc[4];
        GATES(acc, a1hi, a1lo, bias1, Bh, Bl);
        COMBINE(acc, c1[ch], h1v[ch]);
        *(float4*)&htab[16 * ch + e][4 * g] =
            make_float4(h1v[ch][0], h1v[ch][1], h1v[ch][2], h1v[ch][3]);
    }

    // ---- head: fc_h (16->8) + ReLU, fc_o (8->1) ----
    __syncthreads();
    if (lane < EPB) {
        const int ee = lane;
        float hv[16];
        #pragma unroll
        for (int k = 0; k < 16; ++k) hv[k] = htab[ee][k];
        float z[8];
        #pragma unroll
        for (int p = 0; p < 8; ++p) {
            float acc = fc_h_b[p];
            #pragma unroll
            for (int k = 0; k < 16; ++k) acc = fmaf(fc_h_w[p * 16 + k], hv[k], acc);
            z[p] = fmaxf(acc, 0.0f);
        }
        float o = fc_o_b[0];
        #pragma unroll
        for (int p = 0; p < 8; ++p) o = fmaf(fc_o_w[p], z[p], o);
        if (base + ee < B) out[base + ee] = o;
    }
}

extern "C" void kernel_launch(void* const* d_in, const int* in_sizes, int n_in,
                              void* d_out, int out_size, void* d_ws, size_t ws_size,
                              hipStream_t stream) {
    const float* x      = (const float*)d_in[0];
    const float* w_in   = (const float*)d_in[1];
    const float* b_in   = (const float*)d_in[2];
    const float* w_ih0  = (const float*)d_in[3];
    const float* w_hh0  = (const float*)d_in[4];
    const float* b_ih0  = (const float*)d_in[5];
    const float* b_hh0  = (const float*)d_in[6];
    const float* w_ih1  = (const float*)d_in[7];
    const float* w_hh1  = (const float*)d_in[8];
    const float* b_ih1  = (const float*)d_in[9];
    const float* b_hh1  = (const float*)d_in[10];
    const float* fc_h_w = (const float*)d_in[11];
    const float* fc_h_b = (const float*)d_in[12];
    const float* fc_o_w = (const float*)d_in[13];
    const float* fc_o_b = (const float*)d_in[14];

    const int B = out_size;                 // x is [B,T,1]
    const int T = in_sizes[0] / (B > 0 ? B : 1);
    const int grid = (B + EPB - 1) / EPB;   // 256 blocks at B=8192

    hipLaunchKernelGGL(lstm_swp2, dim3(grid), dim3(64), 0, stream,
                       x, w_in, b_in, w_ih0, w_hh0, b_ih0, b_hh0,
                       w_ih1, w_hh1, b_ih1, b_hh1, fc_h_w, fc_h_b,
                       fc_o_w, fc_o_b, (float*)d_out, B, T);
}

// Round 16
// 202.177 us; speedup vs baseline: 1.8734x; 1.8734x over previous
//
#include <hip/hip_runtime.h>
#include <math.h>

// LSTMLightweight on MI355X (R16 = R14 + p-plane-outer MFMA issue order).
//   x[B,T,1] -> linear_in(1->16)+ReLU -> LSTM0(16) -> LSTM1(16) -> fc(16->8)+ReLU -> fc(8->1)
// R15 lesson: 2 chains -> 4 live acc sets blew the 128-reg wall; chains fully
// serialized (per-chain step unchanged). Width is not free; stay 1 chain (~90
// honest regs) and shorten the chain instead.
// R14's GATES emits each tile's 3 MFMAs same-acc back-to-back -> program order
// serializes on MFMA write->read latency ~8x/step. R16 reorders issue into
// p-planes: all 8 tiles' (both layers) plane-0 MFMAs, then plane-1, then
// plane-2: same-acc distance = 8 independent MFMAs >> MFMA latency, with only
// 2 acc sets (32 regs) live. Combines interleave L0/L1 per q.
// Math identical to R12/R14 (absmax 2e-3): K-permuted A so B is lane-local
// (k=8g+i -> W_ih[.][4g+i] | W_hh[.][4g+i-4]; D row=4*(lane>>4)+q, col=lane&15),
// split-bf16 3-product MFMA, bias in C-init.

#define L2E 1.4426950408889634f
#define EPB 16        // elements per wave (= MFMA N)

typedef short bf16x8 __attribute__((ext_vector_type(8)));
typedef float f32x4  __attribute__((ext_vector_type(4)));
typedef int   i32x4  __attribute__((ext_vector_type(4)));

__device__ __forceinline__ float sigm(float v) {
    return __builtin_amdgcn_rcpf(1.0f + __builtin_amdgcn_exp2f(-L2E * v));
}
__device__ __forceinline__ float tanh_(float v) {
    // tanh(v) = 1 - 2/(exp(2v)+1); saturates correctly at +-inf
    return 1.0f - 2.0f * __builtin_amdgcn_rcpf(1.0f + __builtin_amdgcn_exp2f((2.0f * L2E) * v));
}
// bf16 split helpers (truncation split: hi = top 16 bits; lo = bf16(v - hi))
__device__ __forceinline__ float hif(float a) {
    return __uint_as_float(__float_as_uint(a) & 0xFFFF0000u);
}
__device__ __forceinline__ unsigned pk2hi(float a, float b) {
    return (__float_as_uint(a) >> 16) | (__float_as_uint(b) & 0xFFFF0000u);
}
__device__ __forceinline__ unsigned pk2lo(float a, float b) {
    const float ra = a - hif(a), rb = b - hif(b);
    return (__float_as_uint(ra) >> 16) | (__float_as_uint(rb) & 0xFFFF0000u);
}
__device__ __forceinline__ short bhi(float a) { return (short)(__float_as_uint(a) >> 16); }
__device__ __forceinline__ bf16x8 mkfrag(unsigned w0, unsigned w1, unsigned w2, unsigned w3) {
    i32x4 t = {(int)w0, (int)w1, (int)w2, (int)w3};
    return __builtin_bit_cast(bf16x8, t);
}

// prologue/epilogue use the simple chained order (off the hot path)
#define GATES(ACC, AHI, ALO, BIAS, BH, BL)                                             \
    _Pragma("unroll")                                                                  \
    for (int m = 0; m < 4; ++m) {                                                      \
        ACC[m] = BIAS[m];                                                              \
        ACC[m] = __builtin_amdgcn_mfma_f32_16x16x32_bf16(ALO[m], BH, ACC[m], 0, 0, 0); \
        ACC[m] = __builtin_amdgcn_mfma_f32_16x16x32_bf16(AHI[m], BL, ACC[m], 0, 0, 0); \
        ACC[m] = __builtin_amdgcn_mfma_f32_16x16x32_bf16(AHI[m], BH, ACC[m], 0, 0, 0); \
    }

#define COMBINE(ACC, CC, HV)                                                           \
    _Pragma("unroll")                                                                  \
    for (int q = 0; q < 4; ++q) {                                                      \
        const float ig_ = sigm(ACC[0][q]);                                             \
        const float fg_ = sigm(ACC[1][q]);                                             \
        const float gv_ = tanh_(ACC[2][q]);                                            \
        const float og_ = sigm(ACC[3][q]);                                             \
        CC[q] = fmaf(fg_, CC[q], ig_ * gv_);                                           \
        HV[q] = og_ * tanh_(CC[q]);                                                    \
    }

__global__ __launch_bounds__(64) void lstm_swp3(
    const float* __restrict__ x,
    const float* __restrict__ w_in, const float* __restrict__ b_in,
    const float* __restrict__ w_ih0, const float* __restrict__ w_hh0,
    const float* __restrict__ b_ih0, const float* __restrict__ b_hh0,
    const float* __restrict__ w_ih1, const float* __restrict__ w_hh1,
    const float* __restrict__ b_ih1, const float* __restrict__ b_hh1,
    const float* __restrict__ fc_h_w, const float* __restrict__ fc_h_b,
    const float* __restrict__ fc_o_w, const float* __restrict__ fc_o_b,
    float* __restrict__ out, int B, int T)
{
    const int lane = threadIdx.x;        // 0..63
    const int e    = lane & 15;          // element column (= A row within tile)
    const int g    = lane >> 4;          // k-group / D-row group
    const int base = blockIdx.x * EPB;
    int rowe = base + e; if (rowe >= B) rowe = B - 1;

    __shared__ float htab[EPB][16];      // head exchange only

    // ---- A-fragments, K-permuted, split bf16 (MFMA operands: AGPR-free) ----
    bf16x8 a0hi[4], a0lo[4], a1hi[4], a1lo[4];
    f32x4  bias0[4], bias1[4];
    #pragma unroll
    for (int m = 0; m < 4; ++m) {
        const int r = 16 * m + e;
        #pragma unroll
        for (int i = 0; i < 8; ++i) {
            const float w0 = (i < 4) ? w_ih0[r * 16 + 4 * g + i]
                                     : w_hh0[r * 16 + 4 * g + (i - 4)];
            const float w1 = (i < 4) ? w_ih1[r * 16 + 4 * g + i]
                                     : w_hh1[r * 16 + 4 * g + (i - 4)];
            a0hi[m][i] = bhi(w0);  a0lo[m][i] = bhi(w0 - hif(w0));
            a1hi[m][i] = bhi(w1);  a1lo[m][i] = bhi(w1 - hif(w1));
        }
        const int rd = 16 * m + 4 * g;
        #pragma unroll
        for (int q = 0; q < 4; ++q) {
            bias0[m][q] = b_ih0[rd + q] + b_hh0[rd + q];
            bias1[m][q] = b_ih1[rd + q] + b_hh1[rd + q];
        }
    }
    float winq[4], binq[4];
    #pragma unroll
    for (int q = 0; q < 4; ++q) { winq[q] = w_in[4 * g + q]; binq[q] = b_in[4 * g + q]; }

    // ---- state ----
    float c0[4] = {0.f, 0.f, 0.f, 0.f};
    float c1[4] = {0.f, 0.f, 0.f, 0.f};
    float h1v[4] = {0.f, 0.f, 0.f, 0.f};
    unsigned h0h0, h0h1, h0l0, h0l1;                 // h0(t) packs
    unsigned h1h0 = 0u, h1h1 = 0u, h1l0 = 0u, h1l1 = 0u;   // h1(t-1) packs

    const float* xrow = x + (size_t)rowe * T;

    // ---- prologue: L0 at t=0 (h0_{-1}=0) ----
    {
        const float xv = xrow[0];
        float xq[4];
        #pragma unroll
        for (int q = 0; q < 4; ++q) xq[q] = fmaxf(fmaf(xv, winq[q], binq[q]), 0.0f);
        const bf16x8 Bh = mkfrag(pk2hi(xq[0], xq[1]), pk2hi(xq[2], xq[3]), 0u, 0u);
        const bf16x8 Bl = mkfrag(pk2lo(xq[0], xq[1]), pk2lo(xq[2], xq[3]), 0u, 0u);
        f32x4 acc[4];
        GATES(acc, a0hi, a0lo, bias0, Bh, Bl);
        float h0v[4];
        COMBINE(acc, c0, h0v);
        h0h0 = pk2hi(h0v[0], h0v[1]); h0h1 = pk2hi(h0v[2], h0v[3]);
        h0l0 = pk2lo(h0v[0], h0v[1]); h0l1 = pk2lo(h0v[2], h0v[3]);
    }

    float xv1 = xrow[(T > 1) ? 1 : 0];               // x(t+1) for the loop

    // ---- steady state: iteration t does L1(t) || L0(t+1), p-plane MFMA order ----
    for (int t = 0; t < T - 1; ++t) {
        const int tn = (t + 2 < T) ? (t + 2) : (T - 1);
        const float xn = xrow[tn];                   // prefetch x(t+2)

        float xq[4];
        #pragma unroll
        for (int q = 0; q < 4; ++q) xq[q] = fmaxf(fmaf(xv1, winq[q], binq[q]), 0.0f);

        const bf16x8 B0h = mkfrag(pk2hi(xq[0], xq[1]), pk2hi(xq[2], xq[3]), h0h0, h0h1);
        const bf16x8 B0l = mkfrag(pk2lo(xq[0], xq[1]), pk2lo(xq[2], xq[3]), h0l0, h0l1);
        const bf16x8 B1h = mkfrag(h0h0, h0h1, h1h0, h1h1);
        const bf16x8 B1l = mkfrag(h0l0, h0l1, h1l0, h1l1);

        f32x4 acc0[4], acc1[4];
        #pragma unroll
        for (int m = 0; m < 4; ++m) { acc0[m] = bias0[m]; acc1[m] = bias1[m]; }

        // p-plane 0: Alo·Bh — 8 independent MFMAs (same-acc distance = 8)
        #pragma unroll
        for (int m = 0; m < 4; ++m)
            acc0[m] = __builtin_amdgcn_mfma_f32_16x16x32_bf16(a0lo[m], B0h, acc0[m], 0, 0, 0);
        #pragma unroll
        for (int m = 0; m < 4; ++m)
            acc1[m] = __builtin_amdgcn_mfma_f32_16x16x32_bf16(a1lo[m], B1h, acc1[m], 0, 0, 0);
        // p-plane 1: Ahi·Bl
        #pragma unroll
        for (int m = 0; m < 4; ++m)
            acc0[m] = __builtin_amdgcn_mfma_f32_16x16x32_bf16(a0hi[m], B0l, acc0[m], 0, 0, 0);
        #pragma unroll
        for (int m = 0; m < 4; ++m)
            acc1[m] = __builtin_amdgcn_mfma_f32_16x16x32_bf16(a1hi[m], B1l, acc1[m], 0, 0, 0);
        // p-plane 2: Ahi·Bh
        #pragma unroll
        for (int m = 0; m < 4; ++m)
            acc0[m] = __builtin_amdgcn_mfma_f32_16x16x32_bf16(a0hi[m], B0h, acc0[m], 0, 0, 0);
        #pragma unroll
        for (int m = 0; m < 4; ++m)
            acc1[m] = __builtin_amdgcn_mfma_f32_16x16x32_bf16(a1hi[m], B1h, acc1[m], 0, 0, 0);

        // combines: L0/L1 interleaved per q (independent trans chains overlap)
        float h0v[4];
        #pragma unroll
        for (int q = 0; q < 4; ++q) {
            const float i0 = sigm(acc0[0][q]);
            const float i1 = sigm(acc1[0][q]);
            const float f0 = sigm(acc0[1][q]);
            const float f1 = sigm(acc1[1][q]);
            const float g0 = tanh_(acc0[2][q]);
            const float g1 = tanh_(acc1[2][q]);
            const float o0 = sigm(acc0[3][q]);
            const float o1 = sigm(acc1[3][q]);
            c0[q] = fmaf(f0, c0[q], i0 * g0);
            c1[q] = fmaf(f1, c1[q], i1 * g1);
            h0v[q] = o0 * tanh_(c0[q]);
            h1v[q] = o1 * tanh_(c1[q]);
        }

        h0h0 = pk2hi(h0v[0], h0v[1]); h0h1 = pk2hi(h0v[2], h0v[3]);
        h0l0 = pk2lo(h0v[0], h0v[1]); h0l1 = pk2lo(h0v[2], h0v[3]);
        h1h0 = pk2hi(h1v[0], h1v[1]); h1h1 = pk2hi(h1v[2], h1v[3]);
        h1l0 = pk2lo(h1v[0], h1v[1]); h1l1 = pk2lo(h1v[2], h1v[3]);
        xv1 = xn;
    }

    // ---- epilogue: L1(T-1) from h0(T-1), h1(T-2) ----
    {
        const bf16x8 Bh = mkfrag(h0h0, h0h1, h1h0, h1h1);
        const bf16x8 Bl = mkfrag(h0l0, h0l1, h1l0, h1l1);
        f32x4 acc[4];
        GATES(acc, a1hi, a1lo, bias1, Bh, Bl);
        COMBINE(acc, c1, h1v);                       // final h1
    }

    // ---- head: fc_h (16->8) + ReLU, fc_o (8->1) ----
    *(float4*)&htab[e][4 * g] = make_float4(h1v[0], h1v[1], h1v[2], h1v[3]);
    __syncthreads();
    if (lane < EPB) {
        const int ee = lane;
        float hv[16];
        #pragma unroll
        for (int k = 0; k < 16; ++k) hv[k] = htab[ee][k];
        float z[8];
        #pragma unroll
        for (int p = 0; p < 8; ++p) {
            float acc = fc_h_b[p];
            #pragma unroll
            for (int k = 0; k < 16; ++k) acc = fmaf(fc_h_w[p * 16 + k], hv[k], acc);
            z[p] = fmaxf(acc, 0.0f);
        }
        float o = fc_o_b[0];
        #pragma unroll
        for (int p = 0; p < 8; ++p) o = fmaf(fc_o_w[p], z[p], o);
        if (base + ee < B) out[base + ee] = o;
    }
}

extern "C" void kernel_launch(void* const* d_in, const int* in_sizes, int n_in,
                              void* d_out, int out_size, void* d_ws, size_t ws_size,
                              hipStream_t stream) {
    const float* x      = (const float*)d_in[0];
    const float* w_in   = (const float*)d_in[1];
    const float* b_in   = (const float*)d_in[2];
    const float* w_ih0  = (const float*)d_in[3];
    const float* w_hh0  = (const float*)d_in[4];
    const float* b_ih0  = (const float*)d_in[5];
    const float* b_hh0  = (const float*)d_in[6];
    const float* w_ih1  = (const float*)d_in[7];
    const float* w_hh1  = (const float*)d_in[8];
    const float* b_ih1  = (const float*)d_in[9];
    const float* b_hh1  = (const float*)d_in[10];
    const float* fc_h_w = (const float*)d_in[11];
    const float* fc_h_b = (const float*)d_in[12];
    const float* fc_o_w = (const float*)d_in[13];
    const float* fc_o_b = (const float*)d_in[14];

    const int B = out_size;                 // x is [B,T,1]
    const int T = in_sizes[0] / (B > 0 ? B : 1);
    const int grid = (B + EPB - 1) / EPB;   // 512 blocks at B=8192

    hipLaunchKernelGGL(lstm_swp3, dim3(grid), dim3(64), 0, stream,
                       x, w_in, b_in, w_ih0, w_hh0, b_ih0, b_hh0,
                       w_ih1, w_hh1, b_ih1, b_hh1, fc_h_w, fc_h_b,
                       fc_o_w, fc_o_b, (float*)d_out, B, T);
}